// Round 1
// baseline (2123.978 us; speedup 1.0000x reference)
//
#include <hip/hip_runtime.h>
#include <hip/hip_bf16.h>

#define TOK 2048      // B*S
#define DIM 1024      // D
#define HID 4096      // H
#define NE  8         // experts
#define BM 64
#define BN 64
#define BK 16

// ---------------- router: logits, sigmoid, top-2, weights ----------------
__global__ void router_kernel(const float* __restrict__ x,
                              const float* __restrict__ rw,
                              const float* __restrict__ rb,
                              int* __restrict__ counts,
                              float* __restrict__ tok_ss,
                              int* __restrict__ top_e,
                              float* __restrict__ top_w) {
  const int t = blockIdx.x;       // one token per block (64 threads = 1 wave)
  const int lane = threadIdx.x;
  float acc[NE];
#pragma unroll
  for (int e = 0; e < NE; ++e) acc[e] = 0.f;
  const float* xr = x + (size_t)t * DIM;
  for (int d = lane; d < DIM; d += 64) {
    float xv = xr[d];
    const float* w = rw + (size_t)d * NE;
#pragma unroll
    for (int e = 0; e < NE; ++e) acc[e] += xv * w[e];
  }
#pragma unroll
  for (int e = 0; e < NE; ++e) {
    float v = acc[e];
#pragma unroll
    for (int off = 32; off > 0; off >>= 1) v += __shfl_down(v, off, 64);
    acc[e] = v;
  }
  if (lane == 0) {
    float sc[NE];
    float ss = 0.f;
#pragma unroll
    for (int e = 0; e < NE; ++e) {
      float lg = acc[e] + rb[e];
      ss += lg * lg;
      sc[e] = 1.f / (1.f + expf(-lg));
    }
    tok_ss[t] = ss;
    int i0 = 0;
#pragma unroll
    for (int e = 1; e < NE; ++e) if (sc[e] > sc[i0]) i0 = e;
    int i1 = (i0 == 0) ? 1 : 0;
#pragma unroll
    for (int e = 0; e < NE; ++e) if (e != i0 && sc[e] > sc[i1]) i1 = e;
    float s0 = sc[i0], s1 = sc[i1];
    float inv = 1.f / (s0 + s1 + 1e-6f);
    top_e[t * 2 + 0] = i0;
    top_e[t * 2 + 1] = i1;
    top_w[t * 2 + 0] = s0 * inv;
    top_w[t * 2 + 1] = s1 * inv;
    atomicAdd(&counts[i0], 1);
    atomicAdd(&counts[i1], 1);
  }
}

__global__ void zero_kernel(int* __restrict__ counts) {
  if (threadIdx.x < NE) counts[threadIdx.x] = 0;
}

__global__ void scan_kernel(const int* __restrict__ counts,
                            int* __restrict__ offsets,
                            int* __restrict__ fill) {
  if (threadIdx.x == 0) {
    int o = 0;
    for (int e = 0; e < NE; ++e) { offsets[e] = o; o += counts[e]; fill[e] = 0; }
    offsets[NE] = o;
  }
}

__global__ void assign_kernel(const int* __restrict__ top_e,
                              const float* __restrict__ top_w,
                              const int* __restrict__ offsets,
                              int* __restrict__ fill,
                              int* __restrict__ list_tok,
                              float* __restrict__ list_w,
                              int* __restrict__ pair_pos) {
  int i = blockIdx.x * blockDim.x + threadIdx.x;  // over TOK*2 slots
  if (i >= TOK * 2) return;
  int e = top_e[i];
  int pos = atomicAdd(&fill[e], 1);
  int idx = offsets[e] + pos;
  list_tok[idx] = i >> 1;
  list_w[idx] = top_w[i];
  pair_pos[i] = idx;
}

// deterministic fixed-tree reduction for aux loss
__global__ void aux_kernel(const float* __restrict__ tok_ss, float* __restrict__ out_aux) {
  __shared__ float sm[256];
  float s = 0.f;
  for (int t = threadIdx.x; t < TOK; t += 256) s += tok_ss[t];
  sm[threadIdx.x] = s;
  __syncthreads();
  for (int w = 128; w > 0; w >>= 1) {
    if (threadIdx.x < w) sm[threadIdx.x] += sm[threadIdx.x + w];
    __syncthreads();
  }
  if (threadIdx.x == 0) *out_aux = 0.01f * sm[0] / (float)(TOK * NE);
}

// ---------------- GEMM1 + SwiGLU: h = silu(X@W1) * (X@W2) ----------------
__global__ __launch_bounds__(256)
void gemm1_kernel(const float* __restrict__ x, const float* __restrict__ w12,
                  const int* __restrict__ offsets, const int* __restrict__ list_tok,
                  float* __restrict__ hbuf) {
  __shared__ float As[BK][BM];
  __shared__ float Bs1[BK][BN];
  __shared__ float Bs2[BK][BN];
  __shared__ int stok[BM];

  const int e = blockIdx.y >> 5;      // TOK/BM == 32 row-tiles per expert
  const int rt = blockIdx.y & 31;
  const int rowstart = offsets[e] + rt * BM;
  const int rowend = offsets[e + 1];
  if (rowstart >= rowend) return;
  const int j0 = blockIdx.x * BN;
  const int tid = threadIdx.x;
  const int tx = tid & 15, ty = tid >> 4;

  if (tid < BM) {
    int r = rowstart + tid;
    stok[tid] = list_tok[(r < rowend) ? r : rowstart];
  }
  __syncthreads();

  float acc1[4][4] = {};
  float acc2[4][4] = {};
  const float* wbase = w12 + (size_t)e * DIM * (2 * HID);

  for (int k0 = 0; k0 < DIM; k0 += BK) {
#pragma unroll
    for (int i = 0; i < (BM * BK) / 256; ++i) {
      int idx = tid + i * 256;
      int m = idx >> 4, k = idx & 15;
      As[k][m] = x[(size_t)stok[m] * DIM + k0 + k];
    }
#pragma unroll
    for (int i = 0; i < (BK * BN) / 256; ++i) {
      int idx = tid + i * 256;
      int k = idx >> 6, j = idx & 63;
      const float* wp = wbase + (size_t)(k0 + k) * (2 * HID) + j0 + j;
      Bs1[k][j] = wp[0];
      Bs2[k][j] = wp[HID];
    }
    __syncthreads();
#pragma unroll
    for (int k = 0; k < BK; ++k) {
      float a[4], b1[4], b2[4];
#pragma unroll
      for (int i = 0; i < 4; ++i) a[i] = As[k][ty * 4 + i];
#pragma unroll
      for (int j = 0; j < 4; ++j) { b1[j] = Bs1[k][tx * 4 + j]; b2[j] = Bs2[k][tx * 4 + j]; }
#pragma unroll
      for (int i = 0; i < 4; ++i)
#pragma unroll
        for (int j = 0; j < 4; ++j) {
          acc1[i][j] += a[i] * b1[j];
          acc2[i][j] += a[i] * b2[j];
        }
    }
    __syncthreads();
  }

#pragma unroll
  for (int i = 0; i < 4; ++i) {
    int r = rowstart + ty * 4 + i;
    if (r < rowend) {
#pragma unroll
      for (int j = 0; j < 4; ++j) {
        float v1 = acc1[i][j];
        float v2 = acc2[i][j];
        float hv = (v1 / (1.f + expf(-v1))) * v2;  // silu(v1)*v2
        hbuf[(size_t)r * HID + j0 + tx * 4 + j] = hv;
      }
    }
  }
}

// ---------------- GEMM2 + per-row scale: pairout = w * (h @ W3) ----------------
__global__ __launch_bounds__(256)
void gemm2_kernel(const float* __restrict__ hbuf, const float* __restrict__ w3,
                  const int* __restrict__ offsets, const float* __restrict__ list_w,
                  float* __restrict__ pairout) {
  __shared__ float As[BK][BM];
  __shared__ float Bs[BK][BN];
  const int e = blockIdx.y >> 5;
  const int rt = blockIdx.y & 31;
  const int rowstart = offsets[e] + rt * BM;
  const int rowend = offsets[e + 1];
  if (rowstart >= rowend) return;
  const int j0 = blockIdx.x * BN;
  const int tid = threadIdx.x;
  const int tx = tid & 15, ty = tid >> 4;

  float acc[4][4] = {};
  const float* wbase = w3 + (size_t)e * HID * DIM;

  for (int k0 = 0; k0 < HID; k0 += BK) {
#pragma unroll
    for (int i = 0; i < (BM * BK) / 256; ++i) {
      int idx = tid + i * 256;
      int m = idx >> 4, k = idx & 15;
      int r = rowstart + m;
      As[k][m] = (r < rowend) ? hbuf[(size_t)r * HID + k0 + k] : 0.f;
    }
#pragma unroll
    for (int i = 0; i < (BK * BN) / 256; ++i) {
      int idx = tid + i * 256;
      int k = idx >> 6, j = idx & 63;
      Bs[k][j] = wbase[(size_t)(k0 + k) * DIM + j0 + j];
    }
    __syncthreads();
#pragma unroll
    for (int k = 0; k < BK; ++k) {
      float a[4], b[4];
#pragma unroll
      for (int i = 0; i < 4; ++i) a[i] = As[k][ty * 4 + i];
#pragma unroll
      for (int j = 0; j < 4; ++j) b[j] = Bs[k][tx * 4 + j];
#pragma unroll
      for (int i = 0; i < 4; ++i)
#pragma unroll
        for (int j = 0; j < 4; ++j) acc[i][j] += a[i] * b[j];
    }
    __syncthreads();
  }

#pragma unroll
  for (int i = 0; i < 4; ++i) {
    int r = rowstart + ty * 4 + i;
    if (r < rowend) {
      float w = list_w[r];
#pragma unroll
      for (int j = 0; j < 4; ++j)
        pairout[(size_t)r * DIM + j0 + tx * 4 + j] = w * acc[i][j];
    }
  }
}

// ---------------- combine the two routed slots per token ----------------
__global__ void combine_kernel(const float* __restrict__ pairout,
                               const int* __restrict__ pair_pos,
                               float* __restrict__ out) {
  int i = blockIdx.x * blockDim.x + threadIdx.x;  // over TOK * DIM/4
  if (i >= TOK * (DIM / 4)) return;
  int t = i / (DIM / 4);
  int dv = i % (DIM / 4);
  int p0 = pair_pos[t * 2 + 0];
  int p1 = pair_pos[t * 2 + 1];
  float4 a = ((const float4*)(pairout + (size_t)p0 * DIM))[dv];
  float4 b = ((const float4*)(pairout + (size_t)p1 * DIM))[dv];
  float4 o;
  o.x = a.x + b.x; o.y = a.y + b.y; o.z = a.z + b.z; o.w = a.w + b.w;
  ((float4*)out)[i] = o;
}

extern "C" void kernel_launch(void* const* d_in, const int* in_sizes, int n_in,
                              void* d_out, int out_size, void* d_ws, size_t ws_size,
                              hipStream_t stream) {
  const float* x   = (const float*)d_in[0];
  const float* rw  = (const float*)d_in[1];
  const float* rb  = (const float*)d_in[2];
  const float* w12 = (const float*)d_in[3];
  const float* w3  = (const float*)d_in[4];
  float* out = (float*)d_out;

  char* ws = (char*)d_ws;
  size_t off = 0;
  auto alloc = [&](size_t bytes) {
    void* p = ws + off;
    off = (off + bytes + 255) & ~255ULL;
    return p;
  };
  int*   counts   = (int*)alloc(NE * 4);
  int*   fill     = (int*)alloc(NE * 4);
  int*   offsets  = (int*)alloc((NE + 1) * 4);
  float* tok_ss   = (float*)alloc(TOK * 4);
  int*   top_e    = (int*)alloc(TOK * 2 * 4);
  float* top_w    = (float*)alloc(TOK * 2 * 4);
  int*   list_tok = (int*)alloc(TOK * 2 * 4);
  float* list_w   = (float*)alloc(TOK * 2 * 4);
  int*   pair_pos = (int*)alloc(TOK * 2 * 4);
  float* pairout  = (float*)alloc((size_t)TOK * 2 * DIM * 4);   // 16 MB
  float* hbuf     = (float*)alloc((size_t)TOK * 2 * HID * 4);   // 64 MB

  hipLaunchKernelGGL(zero_kernel, dim3(1), dim3(64), 0, stream, counts);
  hipLaunchKernelGGL(router_kernel, dim3(TOK), dim3(64), 0, stream,
                     x, rw, rb, counts, tok_ss, top_e, top_w);
  hipLaunchKernelGGL(scan_kernel, dim3(1), dim3(64), 0, stream, counts, offsets, fill);
  hipLaunchKernelGGL(assign_kernel, dim3((TOK * 2 + 255) / 256), dim3(256), 0, stream,
                     top_e, top_w, offsets, fill, list_tok, list_w, pair_pos);
  hipLaunchKernelGGL(aux_kernel, dim3(1), dim3(256), 0, stream,
                     tok_ss, out + (size_t)TOK * DIM);
  hipLaunchKernelGGL(gemm1_kernel, dim3(HID / BN, NE * (TOK / BM)), dim3(256), 0, stream,
                     x, w12, offsets, list_tok, hbuf);
  hipLaunchKernelGGL(gemm2_kernel, dim3(DIM / BN, NE * (TOK / BM)), dim3(256), 0, stream,
                     hbuf, w3, offsets, list_w, pairout);
  hipLaunchKernelGGL(combine_kernel, dim3((TOK * DIM / 4 + 255) / 256), dim3(256), 0, stream,
                     pairout, pair_pos, out);
}

// Round 2
// 589.768 us; speedup vs baseline: 3.6014x; 3.6014x over previous
//
#include <hip/hip_runtime.h>
#include <hip/hip_bf16.h>

#define TOK 2048      // B*S
#define DIM 1024      // D
#define HID 4096      // H
#define NE  8         // experts

typedef short bf16x8 __attribute__((ext_vector_type(8)));
typedef float f32x4 __attribute__((ext_vector_type(4)));
typedef unsigned short ushort_t;
typedef unsigned int uint_t;

__device__ __forceinline__ ushort_t f2bf(float f) {
  uint_t b = __float_as_uint(f);
  uint_t r = (b + 0x7FFFu + ((b >> 16) & 1u)) >> 16;
  return (ushort_t)r;
}
__device__ __forceinline__ float bf2f(ushort_t u) {
  return __uint_as_float(((uint_t)u) << 16);
}

// ---------------- router: logits, sigmoid, top-2, weights ----------------
__global__ void router_kernel(const float* __restrict__ x,
                              const float* __restrict__ rw,
                              const float* __restrict__ rb,
                              int* __restrict__ counts,
                              float* __restrict__ tok_ss,
                              int* __restrict__ top_e,
                              float* __restrict__ top_w) {
  const int t = blockIdx.x;
  const int lane = threadIdx.x;
  float acc[NE];
#pragma unroll
  for (int e = 0; e < NE; ++e) acc[e] = 0.f;
  const float* xr = x + (size_t)t * DIM;
  for (int d = lane; d < DIM; d += 64) {
    float xv = xr[d];
    const float* w = rw + (size_t)d * NE;
#pragma unroll
    for (int e = 0; e < NE; ++e) acc[e] += xv * w[e];
  }
#pragma unroll
  for (int e = 0; e < NE; ++e) {
    float v = acc[e];
#pragma unroll
    for (int off = 32; off > 0; off >>= 1) v += __shfl_down(v, off, 64);
    acc[e] = v;
  }
  if (lane == 0) {
    float sc[NE];
    float ss = 0.f;
#pragma unroll
    for (int e = 0; e < NE; ++e) {
      float lg = acc[e] + rb[e];
      ss += lg * lg;
      sc[e] = 1.f / (1.f + expf(-lg));
    }
    tok_ss[t] = ss;
    int i0 = 0;
#pragma unroll
    for (int e = 1; e < NE; ++e) if (sc[e] > sc[i0]) i0 = e;
    int i1 = (i0 == 0) ? 1 : 0;
#pragma unroll
    for (int e = 0; e < NE; ++e) if (e != i0 && sc[e] > sc[i1]) i1 = e;
    float s0 = sc[i0], s1 = sc[i1];
    float inv = 1.f / (s0 + s1 + 1e-6f);
    top_e[t * 2 + 0] = i0;
    top_e[t * 2 + 1] = i1;
    top_w[t * 2 + 0] = s0 * inv;
    top_w[t * 2 + 1] = s1 * inv;
    atomicAdd(&counts[i0], 1);
    atomicAdd(&counts[i1], 1);
  }
}

__global__ void zero_kernel(int* __restrict__ counts) {
  if (threadIdx.x < NE) counts[threadIdx.x] = 0;
}

__global__ void scan_kernel(const int* __restrict__ counts,
                            int* __restrict__ offsets,
                            int* __restrict__ fill) {
  if (threadIdx.x == 0) {
    int o = 0;
    for (int e = 0; e < NE; ++e) { offsets[e] = o; o += counts[e]; fill[e] = 0; }
    offsets[NE] = o;
  }
}

__global__ void assign_kernel(const int* __restrict__ top_e,
                              const float* __restrict__ top_w,
                              const int* __restrict__ offsets,
                              int* __restrict__ fill,
                              int* __restrict__ list_tok,
                              float* __restrict__ list_w,
                              int* __restrict__ pair_pos) {
  int i = blockIdx.x * blockDim.x + threadIdx.x;
  if (i >= TOK * 2) return;
  int e = top_e[i];
  int pos = atomicAdd(&fill[e], 1);
  int idx = offsets[e] + pos;
  list_tok[idx] = i >> 1;
  list_w[idx] = top_w[i];
  pair_pos[i] = idx;
}

__global__ void aux_kernel(const float* __restrict__ tok_ss, float* __restrict__ out_aux) {
  __shared__ float sm[256];
  float s = 0.f;
  for (int t = threadIdx.x; t < TOK; t += 256) s += tok_ss[t];
  sm[threadIdx.x] = s;
  __syncthreads();
  for (int w = 128; w > 0; w >>= 1) {
    if (threadIdx.x < w) sm[threadIdx.x] += sm[threadIdx.x + w];
    __syncthreads();
  }
  if (threadIdx.x == 0) *out_aux = 0.01f * sm[0] / (float)(TOK * NE);
}

// =================== FAST PATH (bf16 MFMA) ===================

// x f32 -> xhi/xlo bf16 split
__global__ void convx_kernel(const float* __restrict__ x,
                             ushort_t* __restrict__ xhi, ushort_t* __restrict__ xlo) {
  int i = blockIdx.x * 256 + threadIdx.x;   // over TOK*DIM/4
  float4 v = ((const float4*)x)[i];
  ushort4 h, l;
  h.x = f2bf(v.x); l.x = f2bf(v.x - bf2f(h.x));
  h.y = f2bf(v.y); l.y = f2bf(v.y - bf2f(h.y));
  h.z = f2bf(v.z); l.z = f2bf(v.z - bf2f(h.z));
  h.w = f2bf(v.w); l.w = f2bf(v.w - bf2f(h.w));
  ((ushort4*)xhi)[i] = h;
  ((ushort4*)xlo)[i] = l;
}

// w12 [E][D][2H] f32 -> w1t [E][H][D] bf16, w2t [E][H][D] bf16 (transpose)
__global__ __launch_bounds__(256)
void convw12_kernel(const float* __restrict__ w12,
                    ushort_t* __restrict__ w1t, ushort_t* __restrict__ w2t) {
  __shared__ float tile[64][65];
  const int n0 = blockIdx.x * 64;   // 0..8191 (2H)
  const int d0 = blockIdx.y * 64;   // 0..1023
  const int e  = blockIdx.z;
  const int tid = threadIdx.x;
  const float* src = w12 + ((size_t)e * DIM) * (2 * HID);
#pragma unroll
  for (int i = 0; i < 4; ++i) {
    int u = tid + i * 256;
    int dr = u >> 4, c4 = u & 15;
    float4 v = *(const float4*)&src[(size_t)(d0 + dr) * (2 * HID) + n0 + c4 * 4];
    tile[dr][c4 * 4 + 0] = v.x;
    tile[dr][c4 * 4 + 1] = v.y;
    tile[dr][c4 * 4 + 2] = v.z;
    tile[dr][c4 * 4 + 3] = v.w;
  }
  __syncthreads();
  ushort_t* dst;
  size_t nbase;
  if (n0 < HID) { dst = w1t; nbase = (size_t)e * HID + n0; }
  else          { dst = w2t; nbase = (size_t)e * HID + (n0 - HID); }
#pragma unroll
  for (int i = 0; i < 4; ++i) {
    int u = tid + i * 256;
    int nr = u >> 4, d4 = u & 15;
    ushort4 o;
    o.x = f2bf(tile[d4 * 4 + 0][nr]);
    o.y = f2bf(tile[d4 * 4 + 1][nr]);
    o.z = f2bf(tile[d4 * 4 + 2][nr]);
    o.w = f2bf(tile[d4 * 4 + 3][nr]);
    *(ushort4*)&dst[(nbase + nr) * DIM + d0 + d4 * 4] = o;
  }
}

// w3 [E][H][D] f32 -> w3t [E][D][H] bf16 (transpose)
__global__ __launch_bounds__(256)
void convw3_kernel(const float* __restrict__ w3, ushort_t* __restrict__ w3t) {
  __shared__ float tile[64][65];
  const int d0 = blockIdx.x * 64;   // 0..1023
  const int h0 = blockIdx.y * 64;   // 0..4095
  const int e  = blockIdx.z;
  const int tid = threadIdx.x;
  const float* src = w3 + ((size_t)e * HID) * DIM;
#pragma unroll
  for (int i = 0; i < 4; ++i) {
    int u = tid + i * 256;
    int hr = u >> 4, c4 = u & 15;
    float4 v = *(const float4*)&src[(size_t)(h0 + hr) * DIM + d0 + c4 * 4];
    tile[hr][c4 * 4 + 0] = v.x;
    tile[hr][c4 * 4 + 1] = v.y;
    tile[hr][c4 * 4 + 2] = v.z;
    tile[hr][c4 * 4 + 3] = v.w;
  }
  __syncthreads();
#pragma unroll
  for (int i = 0; i < 4; ++i) {
    int u = tid + i * 256;
    int dr = u >> 4, h4 = u & 15;
    ushort4 o;
    o.x = f2bf(tile[h4 * 4 + 0][dr]);
    o.y = f2bf(tile[h4 * 4 + 1][dr]);
    o.z = f2bf(tile[h4 * 4 + 2][dr]);
    o.w = f2bf(tile[h4 * 4 + 3][dr]);
    *(ushort4*)&w3t[((size_t)e * DIM + d0 + dr) * HID + h0 + h4 * 4] = o;
  }
}

// GEMM1 MFMA: h = silu(X@W1)*(X@W2), A split hi/lo, out h split hi/lo bf16
__global__ __launch_bounds__(256)
void gemm1_mfma(const ushort_t* __restrict__ xhi, const ushort_t* __restrict__ xlo,
                const ushort_t* __restrict__ w1t, const ushort_t* __restrict__ w2t,
                const int* __restrict__ offsets, const int* __restrict__ list_tok,
                ushort_t* __restrict__ hhi, ushort_t* __restrict__ hlo) {
  __shared__ __align__(16) ushort_t Ah[128 * 40];
  __shared__ __align__(16) ushort_t Al[128 * 40];
  __shared__ __align__(16) ushort_t B1[64 * 40];
  __shared__ __align__(16) ushort_t B2[64 * 40];
  __shared__ int stok[128];

  const int e = blockIdx.y >> 4;          // 16 row-tiles of 128 per expert
  const int rt = blockIdx.y & 15;
  const int rowstart = offsets[e] + rt * 128;
  const int rowend = offsets[e + 1];
  if (rowstart >= rowend) return;
  const int h0 = blockIdx.x * 64;
  const int tid = threadIdx.x;
  const int lane = tid & 63, wid = tid >> 6;
  const int wm = wid >> 1, wn = wid & 1;
  const int lr = lane & 15, kh = lane >> 4;

  if (tid < 128) {
    int r = rowstart + tid;
    stok[tid] = list_tok[r < rowend ? r : rowstart];
  }
  __syncthreads();

  f32x4 acc1[4][2], acc2[4][2];
#pragma unroll
  for (int mi = 0; mi < 4; ++mi)
#pragma unroll
    for (int nj = 0; nj < 2; ++nj) {
      acc1[mi][nj] = (f32x4){0.f, 0.f, 0.f, 0.f};
      acc2[mi][nj] = (f32x4){0.f, 0.f, 0.f, 0.f};
    }

  const size_t wbase = ((size_t)e * HID + h0) * DIM;

  for (int k0 = 0; k0 < DIM; k0 += 32) {
#pragma unroll
    for (int i = 0; i < 2; ++i) {
      int u = tid + i * 256;
      int row = u >> 2, seg = u & 3;
      size_t src = (size_t)stok[row] * DIM + k0 + seg * 8;
      *(uint4*)&Ah[row * 40 + seg * 8] = *(const uint4*)&xhi[src];
      *(uint4*)&Al[row * 40 + seg * 8] = *(const uint4*)&xlo[src];
    }
    {
      int row = tid >> 2, seg = tid & 3;
      size_t srcoff = wbase + (size_t)row * DIM + k0 + seg * 8;
      *(uint4*)&B1[row * 40 + seg * 8] = *(const uint4*)&w1t[srcoff];
      *(uint4*)&B2[row * 40 + seg * 8] = *(const uint4*)&w2t[srcoff];
    }
    __syncthreads();

    bf16x8 ah[4], al[4], bf1[2], bf2[2];
#pragma unroll
    for (int mi = 0; mi < 4; ++mi) {
      ah[mi] = *(bf16x8*)&Ah[(wm * 64 + mi * 16 + lr) * 40 + kh * 8];
      al[mi] = *(bf16x8*)&Al[(wm * 64 + mi * 16 + lr) * 40 + kh * 8];
    }
#pragma unroll
    for (int nj = 0; nj < 2; ++nj) {
      bf1[nj] = *(bf16x8*)&B1[(wn * 32 + nj * 16 + lr) * 40 + kh * 8];
      bf2[nj] = *(bf16x8*)&B2[(wn * 32 + nj * 16 + lr) * 40 + kh * 8];
    }
#pragma unroll
    for (int mi = 0; mi < 4; ++mi)
#pragma unroll
      for (int nj = 0; nj < 2; ++nj) {
        acc1[mi][nj] = __builtin_amdgcn_mfma_f32_16x16x32_bf16(ah[mi], bf1[nj], acc1[mi][nj], 0, 0, 0);
        acc1[mi][nj] = __builtin_amdgcn_mfma_f32_16x16x32_bf16(al[mi], bf1[nj], acc1[mi][nj], 0, 0, 0);
        acc2[mi][nj] = __builtin_amdgcn_mfma_f32_16x16x32_bf16(ah[mi], bf2[nj], acc2[mi][nj], 0, 0, 0);
        acc2[mi][nj] = __builtin_amdgcn_mfma_f32_16x16x32_bf16(al[mi], bf2[nj], acc2[mi][nj], 0, 0, 0);
      }
    __syncthreads();
  }

#pragma unroll
  for (int mi = 0; mi < 4; ++mi)
#pragma unroll
    for (int nj = 0; nj < 2; ++nj)
#pragma unroll
      for (int r = 0; r < 4; ++r) {
        int row_t = wm * 64 + mi * 16 + kh * 4 + r;
        int gr = rowstart + row_t;
        if (gr < rowend) {
          int col = h0 + wn * 32 + nj * 16 + lr;
          float v1 = acc1[mi][nj][r], v2 = acc2[mi][nj][r];
          float hv = (v1 / (1.f + expf(-v1))) * v2;
          ushort_t hh = f2bf(hv);
          ushort_t hl = f2bf(hv - bf2f(hh));
          size_t o = (size_t)gr * HID + col;
          hhi[o] = hh;
          hlo[o] = hl;
        }
      }
}

// GEMM2 MFMA: pairout = w * ((hhi+hlo) @ W3), out bf16
__global__ __launch_bounds__(256)
void gemm2_mfma(const ushort_t* __restrict__ hhi, const ushort_t* __restrict__ hlo,
                const ushort_t* __restrict__ w3t,
                const int* __restrict__ offsets, const float* __restrict__ list_w,
                ushort_t* __restrict__ pairout) {
  __shared__ __align__(16) ushort_t Ah[128 * 40];
  __shared__ __align__(16) ushort_t Al[128 * 40];
  __shared__ __align__(16) ushort_t Bs[64 * 40];

  const int e = blockIdx.y >> 4;
  const int rt = blockIdx.y & 15;
  const int rowstart = offsets[e] + rt * 128;
  const int rowend = offsets[e + 1];
  if (rowstart >= rowend) return;
  const int d0 = blockIdx.x * 64;
  const int tid = threadIdx.x;
  const int lane = tid & 63, wid = tid >> 6;
  const int wm = wid >> 1, wn = wid & 1;
  const int lr = lane & 15, kh = lane >> 4;

  f32x4 acc[4][2];
#pragma unroll
  for (int mi = 0; mi < 4; ++mi)
#pragma unroll
    for (int nj = 0; nj < 2; ++nj) acc[mi][nj] = (f32x4){0.f, 0.f, 0.f, 0.f};

  const size_t wb = ((size_t)e * DIM + d0) * HID;

  for (int k0 = 0; k0 < HID; k0 += 32) {
#pragma unroll
    for (int i = 0; i < 2; ++i) {
      int u = tid + i * 256;
      int row = u >> 2, seg = u & 3;
      int gr = rowstart + row;
      if (gr >= rowend) gr = rowstart;
      size_t src = (size_t)gr * HID + k0 + seg * 8;
      *(uint4*)&Ah[row * 40 + seg * 8] = *(const uint4*)&hhi[src];
      *(uint4*)&Al[row * 40 + seg * 8] = *(const uint4*)&hlo[src];
    }
    {
      int row = tid >> 2, seg = tid & 3;
      *(uint4*)&Bs[row * 40 + seg * 8] = *(const uint4*)&w3t[wb + (size_t)row * HID + k0 + seg * 8];
    }
    __syncthreads();

    bf16x8 ah[4], al[4], bf[2];
#pragma unroll
    for (int mi = 0; mi < 4; ++mi) {
      ah[mi] = *(bf16x8*)&Ah[(wm * 64 + mi * 16 + lr) * 40 + kh * 8];
      al[mi] = *(bf16x8*)&Al[(wm * 64 + mi * 16 + lr) * 40 + kh * 8];
    }
#pragma unroll
    for (int nj = 0; nj < 2; ++nj)
      bf[nj] = *(bf16x8*)&Bs[(wn * 32 + nj * 16 + lr) * 40 + kh * 8];
#pragma unroll
    for (int mi = 0; mi < 4; ++mi)
#pragma unroll
      for (int nj = 0; nj < 2; ++nj) {
        acc[mi][nj] = __builtin_amdgcn_mfma_f32_16x16x32_bf16(ah[mi], bf[nj], acc[mi][nj], 0, 0, 0);
        acc[mi][nj] = __builtin_amdgcn_mfma_f32_16x16x32_bf16(al[mi], bf[nj], acc[mi][nj], 0, 0, 0);
      }
    __syncthreads();
  }

#pragma unroll
  for (int mi = 0; mi < 4; ++mi)
#pragma unroll
    for (int nj = 0; nj < 2; ++nj)
#pragma unroll
      for (int r = 0; r < 4; ++r) {
        int row_t = wm * 64 + mi * 16 + kh * 4 + r;
        int gr = rowstart + row_t;
        if (gr < rowend) {
          int col = d0 + wn * 32 + nj * 16 + lr;
          float v = acc[mi][nj][r] * list_w[gr];
          pairout[(size_t)gr * DIM + col] = f2bf(v);
        }
      }
}

__global__ void combine_bf(const ushort_t* __restrict__ pairout,
                           const int* __restrict__ pair_pos,
                           float* __restrict__ out) {
  int i = blockIdx.x * 256 + threadIdx.x;   // TOK*DIM/4
  int t = i >> 8;                           // DIM/4 = 256
  int dv = i & 255;
  int p0 = pair_pos[2 * t], p1 = pair_pos[2 * t + 1];
  ushort4 a = *(const ushort4*)&pairout[(size_t)p0 * DIM + dv * 4];
  ushort4 b = *(const ushort4*)&pairout[(size_t)p1 * DIM + dv * 4];
  float4 o;
  o.x = bf2f(a.x) + bf2f(b.x);
  o.y = bf2f(a.y) + bf2f(b.y);
  o.z = bf2f(a.z) + bf2f(b.z);
  o.w = bf2f(a.w) + bf2f(b.w);
  ((float4*)out)[i] = o;
}

// =================== FALLBACK PATH (round-1 f32) ===================
#define BM 64
#define BN 64
#define BK 16

__global__ __launch_bounds__(256)
void gemm1_f32(const float* __restrict__ x, const float* __restrict__ w12,
               const int* __restrict__ offsets, const int* __restrict__ list_tok,
               float* __restrict__ hbuf) {
  __shared__ float As[BK][BM];
  __shared__ float Bs1[BK][BN];
  __shared__ float Bs2[BK][BN];
  __shared__ int stok[BM];
  const int e = blockIdx.y >> 5;
  const int rt = blockIdx.y & 31;
  const int rowstart = offsets[e] + rt * BM;
  const int rowend = offsets[e + 1];
  if (rowstart >= rowend) return;
  const int j0 = blockIdx.x * BN;
  const int tid = threadIdx.x;
  const int tx = tid & 15, ty = tid >> 4;
  if (tid < BM) {
    int r = rowstart + tid;
    stok[tid] = list_tok[(r < rowend) ? r : rowstart];
  }
  __syncthreads();
  float acc1[4][4] = {};
  float acc2[4][4] = {};
  const float* wbase = w12 + (size_t)e * DIM * (2 * HID);
  for (int k0 = 0; k0 < DIM; k0 += BK) {
#pragma unroll
    for (int i = 0; i < (BM * BK) / 256; ++i) {
      int idx = tid + i * 256;
      int m = idx >> 4, k = idx & 15;
      As[k][m] = x[(size_t)stok[m] * DIM + k0 + k];
    }
#pragma unroll
    for (int i = 0; i < (BK * BN) / 256; ++i) {
      int idx = tid + i * 256;
      int k = idx >> 6, j = idx & 63;
      const float* wp = wbase + (size_t)(k0 + k) * (2 * HID) + j0 + j;
      Bs1[k][j] = wp[0];
      Bs2[k][j] = wp[HID];
    }
    __syncthreads();
#pragma unroll
    for (int k = 0; k < BK; ++k) {
      float a[4], b1[4], b2[4];
#pragma unroll
      for (int i = 0; i < 4; ++i) a[i] = As[k][ty * 4 + i];
#pragma unroll
      for (int j = 0; j < 4; ++j) { b1[j] = Bs1[k][tx * 4 + j]; b2[j] = Bs2[k][tx * 4 + j]; }
#pragma unroll
      for (int i = 0; i < 4; ++i)
#pragma unroll
        for (int j = 0; j < 4; ++j) {
          acc1[i][j] += a[i] * b1[j];
          acc2[i][j] += a[i] * b2[j];
        }
    }
    __syncthreads();
  }
#pragma unroll
  for (int i = 0; i < 4; ++i) {
    int r = rowstart + ty * 4 + i;
    if (r < rowend) {
#pragma unroll
      for (int j = 0; j < 4; ++j) {
        float v1 = acc1[i][j];
        float v2 = acc2[i][j];
        float hv = (v1 / (1.f + expf(-v1))) * v2;
        hbuf[(size_t)r * HID + j0 + tx * 4 + j] = hv;
      }
    }
  }
}

__global__ __launch_bounds__(256)
void gemm2_f32(const float* __restrict__ hbuf, const float* __restrict__ w3,
               const int* __restrict__ offsets, const float* __restrict__ list_w,
               float* __restrict__ pairout) {
  __shared__ float As[BK][BM];
  __shared__ float Bs[BK][BN];
  const int e = blockIdx.y >> 5;
  const int rt = blockIdx.y & 31;
  const int rowstart = offsets[e] + rt * BM;
  const int rowend = offsets[e + 1];
  if (rowstart >= rowend) return;
  const int j0 = blockIdx.x * BN;
  const int tid = threadIdx.x;
  const int tx = tid & 15, ty = tid >> 4;
  float acc[4][4] = {};
  const float* wbase = w3 + (size_t)e * HID * DIM;
  for (int k0 = 0; k0 < HID; k0 += BK) {
#pragma unroll
    for (int i = 0; i < (BM * BK) / 256; ++i) {
      int idx = tid + i * 256;
      int m = idx >> 4, k = idx & 15;
      int r = rowstart + m;
      As[k][m] = (r < rowend) ? hbuf[(size_t)r * HID + k0 + k] : 0.f;
    }
#pragma unroll
    for (int i = 0; i < (BK * BN) / 256; ++i) {
      int idx = tid + i * 256;
      int k = idx >> 6, j = idx & 63;
      Bs[k][j] = wbase[(size_t)(k0 + k) * DIM + j0 + j];
    }
    __syncthreads();
#pragma unroll
    for (int k = 0; k < BK; ++k) {
      float a[4], b[4];
#pragma unroll
      for (int i = 0; i < 4; ++i) a[i] = As[k][ty * 4 + i];
#pragma unroll
      for (int j = 0; j < 4; ++j) b[j] = Bs[k][tx * 4 + j];
#pragma unroll
      for (int i = 0; i < 4; ++i)
#pragma unroll
        for (int j = 0; j < 4; ++j) acc[i][j] += a[i] * b[j];
    }
    __syncthreads();
  }
#pragma unroll
  for (int i = 0; i < 4; ++i) {
    int r = rowstart + ty * 4 + i;
    if (r < rowend) {
      float w = list_w[r];
#pragma unroll
      for (int j = 0; j < 4; ++j)
        pairout[(size_t)r * DIM + j0 + tx * 4 + j] = w * acc[i][j];
    }
  }
}

__global__ void combine_f32(const float* __restrict__ pairout,
                            const int* __restrict__ pair_pos,
                            float* __restrict__ out) {
  int i = blockIdx.x * blockDim.x + threadIdx.x;
  if (i >= TOK * (DIM / 4)) return;
  int t = i / (DIM / 4);
  int dv = i % (DIM / 4);
  int p0 = pair_pos[t * 2 + 0];
  int p1 = pair_pos[t * 2 + 1];
  float4 a = ((const float4*)(pairout + (size_t)p0 * DIM))[dv];
  float4 b = ((const float4*)(pairout + (size_t)p1 * DIM))[dv];
  float4 o;
  o.x = a.x + b.x; o.y = a.y + b.y; o.z = a.z + b.z; o.w = a.w + b.w;
  ((float4*)out)[i] = o;
}

extern "C" void kernel_launch(void* const* d_in, const int* in_sizes, int n_in,
                              void* d_out, int out_size, void* d_ws, size_t ws_size,
                              hipStream_t stream) {
  const float* x   = (const float*)d_in[0];
  const float* rw  = (const float*)d_in[1];
  const float* rb  = (const float*)d_in[2];
  const float* w12 = (const float*)d_in[3];
  const float* w3  = (const float*)d_in[4];
  float* out = (float*)d_out;

  char* ws = (char*)d_ws;
  size_t off = 0;
  auto alloc = [&](size_t bytes) {
    void* p = ws + off;
    off = (off + bytes + 255) & ~255ULL;
    return p;
  };
  // common small buffers
  int*   counts   = (int*)alloc(NE * 4);
  int*   fill     = (int*)alloc(NE * 4);
  int*   offsets  = (int*)alloc((NE + 1) * 4);
  float* tok_ss   = (float*)alloc(TOK * 4);
  int*   top_e    = (int*)alloc(TOK * 2 * 4);
  float* top_w    = (float*)alloc(TOK * 2 * 4);
  int*   list_tok = (int*)alloc(TOK * 2 * 4);
  float* list_w   = (float*)alloc(TOK * 2 * 4);
  int*   pair_pos = (int*)alloc(TOK * 2 * 4);
  size_t off_small = off;

  // tentative fast-path layout
  ushort_t* xhi  = (ushort_t*)alloc((size_t)TOK * DIM * 2);
  ushort_t* xlo  = (ushort_t*)alloc((size_t)TOK * DIM * 2);
  ushort_t* wreg = (ushort_t*)alloc((size_t)NE * DIM * 2 * HID * 2);  // 128 MB
  ushort_t* hhi  = (ushort_t*)alloc((size_t)TOK * 2 * HID * 2);      // 32 MB
  ushort_t* hlo  = (ushort_t*)alloc((size_t)TOK * 2 * HID * 2);      // 32 MB
  bool fast = (off <= ws_size);

  // common prologue
  hipLaunchKernelGGL(zero_kernel, dim3(1), dim3(64), 0, stream, counts);
  hipLaunchKernelGGL(router_kernel, dim3(TOK), dim3(64), 0, stream,
                     x, rw, rb, counts, tok_ss, top_e, top_w);
  hipLaunchKernelGGL(scan_kernel, dim3(1), dim3(64), 0, stream, counts, offsets, fill);
  hipLaunchKernelGGL(assign_kernel, dim3((TOK * 2 + 255) / 256), dim3(256), 0, stream,
                     top_e, top_w, offsets, fill, list_tok, list_w, pair_pos);
  hipLaunchKernelGGL(aux_kernel, dim3(1), dim3(256), 0, stream,
                     tok_ss, out + (size_t)TOK * DIM);

  if (fast) {
    ushort_t* w1t = wreg;                                   // [E][H][D]
    ushort_t* w2t = wreg + (size_t)NE * HID * DIM;          // [E][H][D]
    ushort_t* w3t = wreg;                                   // [E][D][H] (reuses w1t region after gemm1)
    ushort_t* pairoutb = wreg + (size_t)NE * DIM * HID;     // 8 MB, reuses w2t region

    hipLaunchKernelGGL(convx_kernel, dim3(TOK * DIM / 4 / 256), dim3(256), 0, stream,
                       x, xhi, xlo);
    hipLaunchKernelGGL(convw12_kernel, dim3(2 * HID / 64, DIM / 64, NE), dim3(256), 0, stream,
                       w12, w1t, w2t);
    hipLaunchKernelGGL(gemm1_mfma, dim3(HID / 64, NE * 16), dim3(256), 0, stream,
                       xhi, xlo, w1t, w2t, offsets, list_tok, hhi, hlo);
    hipLaunchKernelGGL(convw3_kernel, dim3(DIM / 64, HID / 64, NE), dim3(256), 0, stream,
                       w3, w3t);
    hipLaunchKernelGGL(gemm2_mfma, dim3(DIM / 64, NE * 16), dim3(256), 0, stream,
                       hhi, hlo, w3t, offsets, list_w, pairoutb);
    hipLaunchKernelGGL(combine_bf, dim3(TOK * DIM / 4 / 256), dim3(256), 0, stream,
                       pairoutb, pair_pos, out);
  } else {
    // fallback f32 path (round-1 proven layout, ~80 MB)
    off = off_small;
    float* pairout = (float*)alloc((size_t)TOK * 2 * DIM * 4);   // 16 MB
    float* hbuf    = (float*)alloc((size_t)TOK * 2 * HID * 4);   // 64 MB

    hipLaunchKernelGGL(gemm1_f32, dim3(HID / BN, NE * (TOK / BM)), dim3(256), 0, stream,
                       x, w12, offsets, list_tok, hbuf);
    hipLaunchKernelGGL(gemm2_f32, dim3(DIM / BN, NE * (TOK / BM)), dim3(256), 0, stream,
                       hbuf, w3, offsets, list_w, pairout);
    hipLaunchKernelGGL(combine_f32, dim3((TOK * DIM / 4 + 255) / 256), dim3(256), 0, stream,
                       pairout, pair_pos, out);
  }
}